// Round 9
// baseline (999.667 us; speedup 1.0000x reference)
//
#include <hip/hip_runtime.h>
#include <hip/hip_bf16.h>

typedef __bf16 bf16;
typedef __attribute__((ext_vector_type(8))) __bf16 bf16x8;
typedef __attribute__((ext_vector_type(4))) float f32x4;

constexpr int D_IN  = 512;
constexpr int D_HID = 256;
constexpr int D_OUT = 32;
constexpr int BM = 64;     // rows per block
constexpr int BK = 64;     // K chunk (two 16x16x32 MFMA deep)
constexpr int HCP = 40;    // Hc chunk-stride (bf16)
constexpr int NSLICE = 8;  // XCD count: writer partitioning
constexpr int SCHB = 2048; // scatter grid-stride span (blocks per slice)

#define GLOBAL_AS(p) ((const __attribute__((address_space(1))) void*)(p))
#define LDS_AS(p)    ((__attribute__((address_space(3))) void*)(p))

// ---------------- prep: W1 -> W1T (bf16, [n][k]), W2 -> W2T (bf16, [n][k]) --
__global__ __launch_bounds__(256) void prep_kernel(
    const float* __restrict__ W1, const float* __restrict__ W2,
    bf16* __restrict__ W1T, bf16* __restrict__ W2T)
{
    int idx = blockIdx.x * 256 + threadIdx.x;
    if (idx < D_IN * D_HID) {
        int k = idx / D_HID, n = idx % D_HID;
        W1T[n * D_IN + k] = (bf16)W1[idx];
    }
    int j = idx - D_IN * D_HID;
    if (j >= 0 && j < D_HID * D_OUT) {
        int k = j / D_OUT, n = j % D_OUT;
        W2T[n * D_HID + k] = (bf16)W2[j];
    }
}

// ---------------- fused MLP: X = relu(feat@W1 + b1) @ W2 + b2 ---------------
// Round-5 verified version, verbatim (122 µs stable): 256 thr, BK=64,
// stage -> sync -> MFMA -> sync; Bsm source-permuted XOR swizzle; GEMM2
// chunk-transposed through Hc (aliases Bsm); W2T B-frags from L2-hot global.
__global__ __launch_bounds__(256) void fused_mlp_kernel(
    const float* __restrict__ feat,
    const bf16* __restrict__ W1T, const bf16* __restrict__ W2T,
    const float* __restrict__ b1, const float* __restrict__ b2,
    float* __restrict__ X, int N)
{
    __shared__ __align__(16) char smem[D_HID * BK * sizeof(bf16)];  // 32 KB
    bf16* Bsm = (bf16*)smem;
    bf16* Hc  = (bf16*)smem;   // aliases Bsm (dead after K-loop)

    const int tid  = threadIdx.x;
    const int wave = tid >> 6;
    const int lane = tid & 63;
    const int ln   = lane & 15;   // MFMA row/col index
    const int q    = lane >> 4;   // quad 0..3
    const int mw   = wave * 16;   // wave's row block within tile
    const int r0   = blockIdx.x * BM;

    f32x4 acc[16] = {};  // 16 n-tiles of 16x16 per wave (full D_HID)

    const long arow = (long)min(r0 + mw + ln, N - 1);
    const float* asrc = feat + arow * D_IN + q * 8;

    for (int k0 = 0; k0 < D_IN; k0 += BK) {   // 8 steps
        // async stage B tile [256][64] from W1T. LDS dest linear (16B*c);
        // GLOBAL slot permuted: phys slot s of row r holds logical s^(r&7).
        #pragma unroll
        for (int i = 0; i < 8; ++i) {
            int c  = i * 256 + wave * 64 + lane;        // 0..2047
            int sl = (c & 7) ^ ((c >> 3) & 7);
            const bf16* gsrc = W1T + ((c >> 3) * D_IN + k0 + sl * 8);
            bf16* lbase = Bsm + (i * 256 + wave * 64) * 8;  // wave-uniform
            __builtin_amdgcn_global_load_lds(GLOBAL_AS(gsrc), LDS_AS(lbase), 16, 0, 0);
        }

        // A fragments for both 32-wide sub-steps: direct global -> registers
        bf16x8 af0, af1;
        {
            float4 f0 = *(const float4*)(asrc + k0);
            float4 f1 = *(const float4*)(asrc + k0 + 4);
            af0[0] = (bf16)f0.x; af0[1] = (bf16)f0.y; af0[2] = (bf16)f0.z; af0[3] = (bf16)f0.w;
            af0[4] = (bf16)f1.x; af0[5] = (bf16)f1.y; af0[6] = (bf16)f1.z; af0[7] = (bf16)f1.w;
            float4 f2 = *(const float4*)(asrc + k0 + 32);
            float4 f3 = *(const float4*)(asrc + k0 + 36);
            af1[0] = (bf16)f2.x; af1[1] = (bf16)f2.y; af1[2] = (bf16)f2.z; af1[3] = (bf16)f2.w;
            af1[4] = (bf16)f3.x; af1[5] = (bf16)f3.y; af1[6] = (bf16)f3.z; af1[7] = (bf16)f3.w;
        }

        __syncthreads();   // drains global_load_lds (compiler vmcnt(0) pre-barrier)

        {
            const int psl0 = (0 * 4 + q) ^ (ln & 7);
            #pragma unroll
            for (int t = 0; t < 16; ++t) {
                bf16x8 bfv = *(const bf16x8*)&Bsm[(t * 16 + ln) * BK + psl0 * 8];
                acc[t] = __builtin_amdgcn_mfma_f32_16x16x32_bf16(af0, bfv, acc[t], 0, 0, 0);
            }
            const int psl1 = (1 * 4 + q) ^ (ln & 7);
            #pragma unroll
            for (int t = 0; t < 16; ++t) {
                bf16x8 bfv = *(const bf16x8*)&Bsm[(t * 16 + ln) * BK + psl1 * 8];
                acc[t] = __builtin_amdgcn_mfma_f32_16x16x32_bf16(af1, bfv, acc[t], 0, 0, 0);
            }
        }
        __syncthreads();   // protect Bsm for next iteration's staging
    }

    // GEMM2: X_tile = relu(h) @ W2, transposed chunkwise through Hc.
    f32x4 acc2[2] = {};
    #pragma unroll
    for (int cc = 0; cc < 8; ++cc) {
        #pragma unroll
        for (int tt = 0; tt < 2; ++tt) {
            int t = cc * 2 + tt;
            float bb = b1[t * 16 + ln];
            #pragma unroll
            for (int i = 0; i < 4; ++i) {
                int row = mw + q * 4 + i;
                float v = acc[t][i] + bb;
                Hc[row * HCP + tt * 16 + ln] = (bf16)fmaxf(v, 0.0f);
            }
        }
        __syncthreads();   // Hc chunk visible
        bf16x8 af2 = *(const bf16x8*)&Hc[(mw + ln) * HCP + q * 8];
        int kg = cc * 32 + q * 8;
        #pragma unroll
        for (int t2 = 0; t2 < 2; ++t2) {
            bf16x8 bfv = *(const bf16x8*)&W2T[(t2 * 16 + ln) * D_HID + kg];
            acc2[t2] = __builtin_amdgcn_mfma_f32_16x16x32_bf16(af2, bfv, acc2[t2], 0, 0, 0);
        }
        __syncthreads();   // before next chunk overwrites Hc
    }

    // Epilogue: X = acc2 + b2 (fp32)
    #pragma unroll
    for (int t = 0; t < 2; ++t) {
        int c = t * 16 + ln;
        float bb = b2[c];
        #pragma unroll
        for (int i = 0; i < 4; ++i) {
            int row = r0 + mw + q * 4 + i;
            if (row < N) X[row * D_OUT + c] = acc2[t][i] + bb;
        }
    }
}

// ---------------- scatter: XCD-sliced fp32-atomic segment-sum ---------------
// Replaces hist+scanABC+reorder+reduce (6 launches). 8 lanes per edge, each
// lane: one f32x4 X-gather + 4 HW f32 atomics. XCD slicing (validated r3):
// each out row-region is written by ONE XCD -> atomic lines L2-local, no
// cross-XCD bouncing; atomics RMW in-cache -> no partial-line dirty
// eviction (round-6's failure mode doesn't apply). X and the 19.2 MB of
// index arrays are L3-resident (8x slice re-read is cheap).
__global__ __launch_bounds__(256) void scatter_kernel(
    const int* __restrict__ Arow, const int* __restrict__ Acol,
    const float* __restrict__ Adata, const float* __restrict__ X,
    float* __restrict__ out, int E, int rps)
{
    int slice = blockIdx.x & (NSLICE - 1);
    int esub  = threadIdx.x >> 3;   // 32 edges per block-chunk
    int dg    = threadIdx.x & 7;    // dim group: dims 4*dg..4*dg+3
    int nch = (E + 31) / 32;
    for (int ch = blockIdx.x >> 3; ch < nch; ch += SCHB) {
        int e = ch * 32 + esub;
        if (e < E) {
            int r = Arow[e];            // broadcast across the 8 dg lanes
            if ((unsigned)(r - slice * rps) < (unsigned)rps) {
                float a   = Adata[e];
                int   col = Acol[e];
                f32x4 x = *(const f32x4*)(X + (long)col * D_OUT + dg * 4);
                float* o = out + (long)r * D_OUT + dg * 4;
                unsafeAtomicAdd(o + 0, a * x[0]);
                unsafeAtomicAdd(o + 1, a * x[1]);
                unsafeAtomicAdd(o + 2, a * x[2]);
                unsafeAtomicAdd(o + 3, a * x[3]);
            }
        }
    }
}

// ---------------- launch ----------------------------------------------------
extern "C" void kernel_launch(void* const* d_in, const int* in_sizes, int n_in,
                              void* d_out, int out_size, void* d_ws, size_t ws_size,
                              hipStream_t stream)
{
    const float* feat  = (const float*)d_in[0];
    const float* Adata = (const float*)d_in[1];
    const float* W1    = (const float*)d_in[2];
    const float* b1    = (const float*)d_in[3];
    const float* W2    = (const float*)d_in[4];
    const float* b2    = (const float*)d_in[5];
    const int*   Arow  = (const int*)d_in[6];
    const int*   Acol  = (const int*)d_in[7];

    const int N = in_sizes[0] / D_IN;
    const int E = in_sizes[1];

    // --- workspace carve-out (256B aligned segments) ---
    char* p = (char*)d_ws;
    auto alloc = [&](size_t bytes) {
        char* q = p;
        p += (bytes + 255) & ~(size_t)255;
        return q;
    };
    float* X   = (float*)alloc((size_t)N * D_OUT * sizeof(float));
    bf16*  W1T = (bf16*) alloc((size_t)D_IN * D_HID * sizeof(bf16));
    bf16*  W2T = (bf16*) alloc((size_t)D_HID * D_OUT * sizeof(bf16));
    (void)ws_size;

    float* out = (float*)d_out;

    int prep_elems = D_IN * D_HID + D_HID * D_OUT;
    prep_kernel<<<(prep_elems + 255) / 256, 256, 0, stream>>>(W1, W2, W1T, W2T);

    fused_mlp_kernel<<<(N + BM - 1) / BM, 256, 0, stream>>>(
        feat, W1T, W2T, b1, b2, X, N);

    hipMemsetAsync(out, 0, (size_t)out_size * sizeof(float), stream);
    int rps = (N + NSLICE - 1) / NSLICE;
    scatter_kernel<<<NSLICE * SCHB, 256, 0, stream>>>(
        Arow, Acol, Adata, X, out, E, rps);
}